// Round 19
// baseline (92.262 us; speedup 1.0000x reference)
//
#include <hip/hip_runtime.h>

typedef unsigned short u16;
typedef unsigned int   u32;
typedef float f32x2 __attribute__((ext_vector_type(2)));

// ---- bf16 helpers ----
__device__ __forceinline__ u16 f2b(float f) {
    u32 u = __float_as_uint(f);
    return (u16)((u + 0x7fffu + ((u >> 16) & 1u)) >> 16);
}
__device__ __forceinline__ u32 pack2f(float a, float b) {
    return (u32)f2b(a) | ((u32)f2b(b) << 16);
}
__device__ __forceinline__ f32x2 unpk2(u32 w) {
    f32x2 r;
    r[0] = __uint_as_float(w << 16);
    r[1] = __uint_as_float(w & 0xffff0000u);
    return r;
}
__device__ __forceinline__ int permc(int c) { return ((c & 7) << 3) | (c >> 3); }
__device__ __forceinline__ f32x2 bc2(float x) { f32x2 r; r[0] = x; r[1] = x; return r; }
__device__ __forceinline__ f32x2 mk2(float a, float b) { f32x2 r; r[0] = a; r[1] = b; return r; }

// packed bf16 dot: c += a.lo*b.lo + a.hi*b.hi  (single-reg operands: keep)
__device__ __forceinline__ void dot2bf(float& c, u32 a, u32 b) {
    asm("v_dot2_f32_bf16 %0, %1, %2, %0" : "+v"(c) : "v"(a), "v"(b));
}
__device__ __forceinline__ u32 cvtpk(float lo, float hi) {
    u32 r;
    asm("v_cvt_pk_bf16_f32 %0, %1, %2" : "=v"(r) : "v"(lo), "v"(hi));
    return r;
}

// ---- DPP cross-lane via BUILTIN (compiler inserts VALU->DPP wait states) ----
template<int CTRL>
__device__ __forceinline__ float dppf(float x) {
    return __int_as_float(__builtin_amdgcn_update_dpp(0, __float_as_int(x), CTRL, 0xf, 0xf, true));
}
__device__ __forceinline__ float gsum8(float x) {
    x += dppf<0xB1>(x);
    x += dppf<0x4E>(x);
    x += dppf<0x141>(x);
    return x;
}
__device__ __forceinline__ float gmax8(float x) {
    x = fmaxf(x, dppf<0xB1>(x));
    x = fmaxf(x, dppf<0x4E>(x));
    x = fmaxf(x, dppf<0x141>(x));
    return x;
}
// slot->h map for the {xor1, xor2, mirror(=xor7)} butterfly: h = phi(r) ^ lane
__device__ __forceinline__ int phi8(int r) { return (r < 4) ? r : (r ^ 3); }

// ======= Kernel 1: q/k/v projections, dot2bf inner loop (R10+, proven) =======
__global__ __launch_bounds__(256) void qkv_kernel(
    const float* __restrict__ feat,
    const float* __restrict__ Wq, const float* __restrict__ bq,
    const float* __restrict__ Wk, const float* __restrict__ bk,
    const float* __restrict__ Wv, const float* __restrict__ bv,
    u16* __restrict__ qt, u16* __restrict__ kvt)
{
    __shared__ u32 wpk[3][32][64];
    __shared__ u32 fpk[32][132];
    const int t = threadIdx.x;
    const int rowbase = blockIdx.x * 128;

    {
        const float* Ws[3] = {Wq, Wk, Wv};
#pragma unroll
        for (int mm = 0; mm < 3; mm++) {
            for (int e = t; e < 512; e += 256) {
                int ip = e >> 4, c4 = (e & 15) * 4;
                float4 wa = *(const float4*)&Ws[mm][(2 * ip) * 64 + c4];
                float4 wb = *(const float4*)&Ws[mm][(2 * ip + 1) * 64 + c4];
                wpk[mm][ip][permc(c4 + 0)] = pack2f(wa.x, wb.x);
                wpk[mm][ip][permc(c4 + 1)] = pack2f(wa.y, wb.y);
                wpk[mm][ip][permc(c4 + 2)] = pack2f(wa.z, wb.z);
                wpk[mm][ip][permc(c4 + 3)] = pack2f(wa.w, wb.w);
            }
        }
    }
    for (int e = t; e < 2048; e += 256) {
        int r = e >> 4, ip2 = (e & 15) * 2;
        float4 v = *(const float4*)&feat[(size_t)(rowbase + r) * 64 + ip2 * 2];
        fpk[ip2][r]     = pack2f(v.x, v.y);
        fpk[ip2 + 1][r] = pack2f(v.z, v.w);
    }
    __syncthreads();

    const int rg = t >> 3;
    const int q8 = t & 7;
    const int c0 = q8 * 8;

    float acc[3][4][8];
    {
        const float* Bs[3] = {bq, bk, bv};
#pragma unroll
        for (int m = 0; m < 3; m++)
#pragma unroll
            for (int x = 0; x < 8; x++) {
                float b = Bs[m][x * 8 + q8];
#pragma unroll
                for (int r = 0; r < 4; r++) acc[m][r][x] = b;
            }
    }

#pragma unroll 2
    for (int ip = 0; ip < 32; ip++) {
        uint4 f4 = *(const uint4*)&fpk[ip][rg * 4];
        u32 fr[4] = {f4.x, f4.y, f4.z, f4.w};
#pragma unroll
        for (int m = 0; m < 3; m++) {
            uint4 wv0 = *(const uint4*)&wpk[m][ip][c0];
            uint4 wv1 = *(const uint4*)&wpk[m][ip][c0 + 4];
            u32 wc[8] = {wv0.x, wv0.y, wv0.z, wv0.w, wv1.x, wv1.y, wv1.z, wv1.w};
#pragma unroll
            for (int r = 0; r < 4; r++)
#pragma unroll
                for (int x = 0; x < 8; x++)
                    dot2bf(acc[m][r][x], fr[r], wc[x]);
        }
    }

#pragma unroll
    for (int r = 0; r < 4; r++) {
        int row = rowbase + rg * 4 + r;
        uint4 oq, ok, ov;
        oq.x = cvtpk(acc[0][r][0], acc[0][r][1]); oq.y = cvtpk(acc[0][r][2], acc[0][r][3]);
        oq.z = cvtpk(acc[0][r][4], acc[0][r][5]); oq.w = cvtpk(acc[0][r][6], acc[0][r][7]);
        ok.x = cvtpk(acc[1][r][0], acc[1][r][1]); ok.y = cvtpk(acc[1][r][2], acc[1][r][3]);
        ok.z = cvtpk(acc[1][r][4], acc[1][r][5]); ok.w = cvtpk(acc[1][r][6], acc[1][r][7]);
        ov.x = cvtpk(acc[2][r][0], acc[2][r][1]); ov.y = cvtpk(acc[2][r][2], acc[2][r][3]);
        ov.z = cvtpk(acc[2][r][4], acc[2][r][5]); ov.w = cvtpk(acc[2][r][6], acc[2][r][7]);
        *(uint4*)&qt [(size_t)row * 64 + c0]       = oq;
        *(uint4*)&kvt[(size_t)row * 128 + c0]      = ok;
        *(uint4*)&kvt[(size_t)row * 128 + 64 + c0] = ov;
    }
}

// ===== Kernel 2: fused gather + attention =====
// R16 EXACTLY (W1 in LDS, P-params in REGISTERS, natural allocation — best
// known: 55.4 us, VGPR 80) + ONE change: p-MLP fold (out = Σsm·v + PB·M +
// Σ_a P_a·S_a; exact algebra, proven safe WITH max-sub in R17). Saves the
// pjs[4] registers and ~12 VALU ops/nbr on the V path.
__global__ __launch_bounds__(256) void attn_kernel(
    const float* __restrict__ point,
    const int*   __restrict__ idx,
    const u16*   __restrict__ qt,
    const u16*   __restrict__ kvt,
    const float* __restrict__ p_w1,   const float* __restrict__ p_b1,
    const float* __restrict__ p_bn_g, const float* __restrict__ p_bn_b,
    const float* __restrict__ p_bn_m, const float* __restrict__ p_bn_v,
    const float* __restrict__ p_w2,   const float* __restrict__ p_b2,
    const float* __restrict__ w_bn1_g, const float* __restrict__ w_bn1_b,
    const float* __restrict__ w_bn1_m, const float* __restrict__ w_bn1_v,
    const float* __restrict__ w_w1,    const float* __restrict__ w_b1,
    const float* __restrict__ w_bn2_g, const float* __restrict__ w_bn2_b,
    const float* __restrict__ w_bn2_m, const float* __restrict__ w_bn2_v,
    const float* __restrict__ w_w2,    const float* __restrict__ w_b2,
    float* __restrict__ out)
{
    __shared__ u32 lds_w1[8 * 36];   // [l8][36]: 32 used + 4 pad
    const int t  = threadIdx.x;
    const int l8 = t & 7;
    const int n  = blockIdx.x * 32 + (t >> 3);
    const float EPS = 1e-5f;

    // stage w_w1 columns (phi-permuted, bf16-paired): 256 values, 1/thread
    {
        int gl8 = t >> 5, iw = t & 31;
        int p = iw >> 3, r = iw & 7;
        int ce = 16 * p + gl8, co = ce + 8;
        int hh = phi8(r) ^ gl8;
        lds_w1[gl8 * 36 + iw] = pack2f(w_w1[ce * 8 + hh], w_w1[co * 8 + hh]);
    }

    // ---- wave-uniform params (SGPR) ----
    float pw1[9];
#pragma unroll
    for (int i = 0; i < 9; i++) pw1[i] = p_w1[i];
    float pb1b[3], pbs[3], pbh[3];
#pragma unroll
    for (int a = 0; a < 3; a++) {
        float s = p_bn_g[a] * rsqrtf(p_bn_v[a] + EPS);
        pb1b[a] = p_b1[a];
        pbs[a]  = s;
        pbh[a]  = p_bn_b[a] - p_bn_m[a] * s;
    }

    // ---- per-lane register params ----
    f32x2 P0[4], P1[4], P2[4], PB[4];
#pragma unroll
    for (int p = 0; p < 4; p++) {
        int ce = 16 * p + l8, co = ce + 8;
        P0[p] = mk2(p_w2[ce],       p_w2[co]);
        P1[p] = mk2(p_w2[64 + ce],  p_w2[64 + co]);
        P2[p] = mk2(p_w2[128 + ce], p_w2[128 + co]);
        PB[p] = mk2(p_b2[ce],       p_b2[co]);
    }
    // bn2 for this lane's h = l8 only (scalar)
    float b2s_l, b2hh_l;
    {
        float s = w_bn2_g[l8] * rsqrtf(w_bn2_v[l8] + EPS);
        b2s_l  = s;
        b2hh_l = (w_bn2_b[l8] - w_bn2_m[l8] * s) + w_b1[l8] * s;
    }
    // w_w2 column l8, ordered by all-gather slot j: h = phi(j)^l8
    u32 ww2xpk[4];
#pragma unroll
    for (int i = 0; i < 4; i++) {
        int h0 = phi8(2 * i)     ^ l8;
        int h1 = phi8(2 * i + 1) ^ l8;
        ww2xpk[i] = pack2f(w_w2[h0 * 8 + l8], w_w2[h1 * 8 + l8]);
    }
    const float wb2l = w_b2[l8];

    // bn1 scale + offset with q folded: w = relu((k+pj)*s2 + qh2)
    f32x2 s2[4], qh2[4];
    {
        uint4 qr = *(const uint4*)&qt[(size_t)n * 64 + l8 * 8];
        const u32* qw = (const u32*)&qr;
#pragma unroll
        for (int p = 0; p < 4; p++) {
            int ce = 16 * p + l8, co = ce + 8;
            float se = w_bn1_g[ce] * rsqrtf(w_bn1_v[ce] + EPS);
            float so = w_bn1_g[co] * rsqrtf(w_bn1_v[co] + EPS);
            float he = w_bn1_b[ce] - w_bn1_m[ce] * se;
            float ho = w_bn1_b[co] - w_bn1_m[co] * so;
            f32x2 q2 = unpk2(qw[p]);
            s2[p]  = mk2(se, so);
            qh2[p] = mk2(he - q2[0] * se, ho - q2[1] * so);
        }
    }

    const float px = point[n * 3], py = point[n * 3 + 1], pz = point[n * 3 + 2];
    f32x2 acc2[4];
#pragma unroll
    for (int p = 0; p < 4; p++) acc2[p] = mk2(0.f, 0.f);
    float S0 = 0.f, S1 = 0.f, S2 = 0.f, M = 0.f;

    __syncthreads();                      // lds_w1 ready
    const u32* wrow = lds_w1 + l8 * 36;   // this lane's w_w1 row base

    // ---- neighbor loop: rolling int4 idx groups, 1-deep kv/point prefetch ----
    uint4 kr, vr;
    float2 jxy;
    float  jz;

    auto proc = [&](int jn) {
        const u16* kpn = kvt + (size_t)jn * 128 + l8 * 8;
        uint4 krn = *(const uint4*)kpn;
        uint4 vrn = *(const uint4*)(kpn + 64);
        float2 jxyn = *(const float2*)&point[jn * 3];
        float  jzn  = point[jn * 3 + 2];

        // linear_p stage 1 (3->3, BN, ReLU)
        float dx = jxy.x - px, dy = jxy.y - py, dz = jz - pz;
        float t0 = fmaxf(0.f, fmaf(fmaf(dz, pw1[6], fmaf(dy, pw1[3], fmaf(dx, pw1[0], pb1b[0]))), pbs[0], pbh[0]));
        float t1 = fmaxf(0.f, fmaf(fmaf(dz, pw1[7], fmaf(dy, pw1[4], fmaf(dx, pw1[1], pb1b[1]))), pbs[1], pbh[1]));
        float t2 = fmaxf(0.f, fmaf(fmaf(dz, pw1[8], fmaf(dy, pw1[5], fmaf(dx, pw1[2], pb1b[2]))), pbs[2], pbh[2]));
        f32x2 tp0 = bc2(t0), tp1 = bc2(t1), tp2 = bc2(t2);

        const u32* kw = (const u32*)&kr;
        float part[8];
#pragma unroll
        for (int h = 0; h < 8; h++) part[h] = 0.f;

#pragma unroll
        for (int p = 0; p < 4; p++) {
            f32x2 pj = PB[p] + tp0 * P0[p] + tp1 * P1[p] + tp2 * P2[p];
            f32x2 kf = unpk2(kw[p]);
            f32x2 w2 = (kf + pj) * s2[p] + qh2[p];
            u32 wpk_ = cvtpk(fmaxf(w2[0], 0.f), fmaxf(w2[1], 0.f));
            uint4 wa  = *(const uint4*)&wrow[p * 8];
            uint4 wb4 = *(const uint4*)&wrow[p * 8 + 4];
            dot2bf(part[0], wpk_, wa.x);
            dot2bf(part[1], wpk_, wa.y);
            dot2bf(part[2], wpk_, wa.z);
            dot2bf(part[3], wpk_, wa.w);
            dot2bf(part[4], wpk_, wb4.x);
            dot2bf(part[5], wpk_, wb4.y);
            dot2bf(part[6], wpk_, wb4.z);
            dot2bf(part[7], wpk_, wb4.w);
        }
        // reduce-scatter (slots: h = phi(r)^lane; stages xor1, xor2, mirror)
        part[0] += dppf<0xB1>(part[1]);
        part[2] += dppf<0xB1>(part[3]);
        part[4] += dppf<0xB1>(part[5]);
        part[6] += dppf<0xB1>(part[7]);
        part[0] += dppf<0x4E>(part[2]);
        part[4] += dppf<0x4E>(part[6]);
        part[0] += dppf<0x141>(part[4]);
        // scalar bn2 for this lane's h = l8
        float wbl = fmaxf(0.f, fmaf(part[0], b2s_l, b2hh_l));
        // all-gather wb across the 8 lanes (slot j holds wb of h = phi(j)^l8)
        float u1 = dppf<0xB1>(wbl);
        float u2 = dppf<0x4E>(wbl);
        float u3 = dppf<0x4E>(u1);
        float u4 = dppf<0x141>(wbl);
        float u5 = dppf<0x141>(u1);
        float u6 = dppf<0x141>(u2);
        float u7 = dppf<0x141>(u3);
        float y = wb2l;
        dot2bf(y, cvtpk(wbl, u1), ww2xpk[0]);
        dot2bf(y, cvtpk(u2, u3), ww2xpk[1]);
        dot2bf(y, cvtpk(u4, u5), ww2xpk[2]);
        dot2bf(y, cvtpk(u6, u7), ww2xpk[3]);

        // softmax over the 8 lanes — WITH max-subtraction (load-bearing)
        float mx = gmax8(y);
        float e  = __expf(y - mx);
        float ssum = gsum8(e);
        float sm = e * __builtin_amdgcn_rcpf(ssum);
        f32x2 sm2 = bc2(sm);

        // p-MLP fold (exact algebra; proven with max-sub in R17)
        M  += sm;
        S0 = fmaf(sm, t0, S0);
        S1 = fmaf(sm, t1, S1);
        S2 = fmaf(sm, t2, S2);

        const u32* vw = (const u32*)&vr;
#pragma unroll
        for (int p = 0; p < 4; p++) acc2[p] += sm2 * unpk2(vw[p]);

        kr = krn; vr = vrn; jxy = jxyn; jz = jzn;
    };

    const int4* idxq = (const int4*)(idx + n * 16);   // 64B-aligned row
    int4 I = idxq[0];
    {
        const u16* kp0 = kvt + (size_t)I.x * 128 + l8 * 8;
        kr  = *(const uint4*)kp0;
        vr  = *(const uint4*)(kp0 + 64);
        jxy = *(const float2*)&point[I.x * 3];
        jz  = point[I.x * 3 + 2];
    }
#pragma unroll
    for (int kg = 0; kg < 4; kg++) {
        int4 In = (kg < 3) ? idxq[kg + 1] : I;   // static offset under unroll
        proc(I.y);
        proc(I.z);
        proc(I.w);
        proc(In.x);   // last group: re-prefetch of a processed nbr, harmless
        I = In;
    }

    // epilogue: acc += PB*M + P0*S0 + P1*S1 + P2*S2
    f32x2 Mb = bc2(M), S0b = bc2(S0), S1b = bc2(S1), S2b = bc2(S2);
#pragma unroll
    for (int p = 0; p < 4; p++) {
        acc2[p] += Mb * PB[p] + S0b * P0[p] + S1b * P1[p] + S2b * P2[p];
        out[(size_t)n * 64 + 16 * p + l8]     = acc2[p][0];
        out[(size_t)n * 64 + 16 * p + 8 + l8] = acc2[p][1];
    }
}

extern "C" void kernel_launch(void* const* d_in, const int* in_sizes, int n_in,
                              void* d_out, int out_size, void* d_ws, size_t ws_size,
                              hipStream_t stream)
{
    const float* point   = (const float*)d_in[0];
    const float* feat    = (const float*)d_in[1];
    const int*   idx     = (const int*)d_in[2];
    const float* Wq      = (const float*)d_in[3];
    const float* bq      = (const float*)d_in[4];
    const float* Wk      = (const float*)d_in[5];
    const float* bk      = (const float*)d_in[6];
    const float* Wv      = (const float*)d_in[7];
    const float* bv      = (const float*)d_in[8];
    const float* p_w1    = (const float*)d_in[9];
    const float* p_b1    = (const float*)d_in[10];
    const float* p_bn_g  = (const float*)d_in[11];
    const float* p_bn_b  = (const float*)d_in[12];
    const float* p_bn_m  = (const float*)d_in[13];
    const float* p_bn_v  = (const float*)d_in[14];
    const float* p_w2    = (const float*)d_in[15];
    const float* p_b2    = (const float*)d_in[16];
    const float* w_bn1_g = (const float*)d_in[17];
    const float* w_bn1_b = (const float*)d_in[18];
    const float* w_bn1_m = (const float*)d_in[19];
    const float* w_bn1_v = (const float*)d_in[20];
    const float* w_w1    = (const float*)d_in[21];
    const float* w_b1    = (const float*)d_in[22];
    const float* w_bn2_g = (const float*)d_in[23];
    const float* w_bn2_b = (const float*)d_in[24];
    const float* w_bn2_m = (const float*)d_in[25];
    const float* w_bn2_v = (const float*)d_in[26];
    const float* w_w2    = (const float*)d_in[27];
    const float* w_b2    = (const float*)d_in[28];
    float* out = (float*)d_out;

    const int N = in_sizes[0] / 3;   // 65536

    u16* kvt = (u16*)d_ws;                       // N*128 bf16
    u16* qt  = (u16*)d_ws + (size_t)N * 128;     // N*64 bf16

    qkv_kernel<<<N / 128, 256, 0, stream>>>(feat, Wq, bq, Wk, bk, Wv, bv, qt, kvt);
    attn_kernel<<<N / 32, 256, 0, stream>>>(point, idx, qt, kvt,
                                            p_w1, p_b1, p_bn_g, p_bn_b, p_bn_m, p_bn_v, p_w2, p_b2,
                                            w_bn1_g, w_bn1_b, w_bn1_m, w_bn1_v, w_w1, w_b1,
                                            w_bn2_g, w_bn2_b, w_bn2_m, w_bn2_v, w_w2, w_b2,
                                            out);
}

// Round 20
// 78.762 us; speedup vs baseline: 1.1714x; 1.1714x over previous
//
#include <hip/hip_runtime.h>

typedef unsigned short u16;
typedef unsigned int   u32;
typedef float f32x2 __attribute__((ext_vector_type(2)));

// ---- bf16 helpers ----
__device__ __forceinline__ u16 f2b(float f) {
    u32 u = __float_as_uint(f);
    return (u16)((u + 0x7fffu + ((u >> 16) & 1u)) >> 16);
}
__device__ __forceinline__ u32 pack2f(float a, float b) {
    return (u32)f2b(a) | ((u32)f2b(b) << 16);
}
__device__ __forceinline__ f32x2 unpk2(u32 w) {
    f32x2 r;
    r[0] = __uint_as_float(w << 16);
    r[1] = __uint_as_float(w & 0xffff0000u);
    return r;
}
__device__ __forceinline__ int permc(int c) { return ((c & 7) << 3) | (c >> 3); }
__device__ __forceinline__ f32x2 bc2(float x) { f32x2 r; r[0] = x; r[1] = x; return r; }
__device__ __forceinline__ f32x2 mk2(float a, float b) { f32x2 r; r[0] = a; r[1] = b; return r; }

// packed bf16 dot: c += a.lo*b.lo + a.hi*b.hi  (single-reg operands: keep)
__device__ __forceinline__ void dot2bf(float& c, u32 a, u32 b) {
    asm("v_dot2_f32_bf16 %0, %1, %2, %0" : "+v"(c) : "v"(a), "v"(b));
}
__device__ __forceinline__ u32 cvtpk(float lo, float hi) {
    u32 r;
    asm("v_cvt_pk_bf16_f32 %0, %1, %2" : "=v"(r) : "v"(lo), "v"(hi));
    return r;
}

// ---- DPP cross-lane via BUILTIN (compiler inserts VALU->DPP wait states) ----
template<int CTRL>
__device__ __forceinline__ float dppf(float x) {
    return __int_as_float(__builtin_amdgcn_update_dpp(0, __float_as_int(x), CTRL, 0xf, 0xf, true));
}
__device__ __forceinline__ float gsum8(float x) {
    x += dppf<0xB1>(x);
    x += dppf<0x4E>(x);
    x += dppf<0x141>(x);
    return x;
}
__device__ __forceinline__ float gmax8(float x) {
    x = fmaxf(x, dppf<0xB1>(x));
    x = fmaxf(x, dppf<0x4E>(x));
    x = fmaxf(x, dppf<0x141>(x));
    return x;
}
// slot->h map for the {xor1, xor2, mirror(=xor7)} butterfly: h = phi(r) ^ lane
__device__ __forceinline__ int phi8(int r) { return (r < 4) ? r : (r ^ 3); }

// ======= Kernel 1: q/k/v projections, dot2bf inner loop (R10+, proven) =======
__global__ __launch_bounds__(256) void qkv_kernel(
    const float* __restrict__ feat,
    const float* __restrict__ Wq, const float* __restrict__ bq,
    const float* __restrict__ Wk, const float* __restrict__ bk,
    const float* __restrict__ Wv, const float* __restrict__ bv,
    u16* __restrict__ qt, u16* __restrict__ kvt)
{
    __shared__ u32 wpk[3][32][64];
    __shared__ u32 fpk[32][132];
    const int t = threadIdx.x;
    const int rowbase = blockIdx.x * 128;

    {
        const float* Ws[3] = {Wq, Wk, Wv};
#pragma unroll
        for (int mm = 0; mm < 3; mm++) {
            for (int e = t; e < 512; e += 256) {
                int ip = e >> 4, c4 = (e & 15) * 4;
                float4 wa = *(const float4*)&Ws[mm][(2 * ip) * 64 + c4];
                float4 wb = *(const float4*)&Ws[mm][(2 * ip + 1) * 64 + c4];
                wpk[mm][ip][permc(c4 + 0)] = pack2f(wa.x, wb.x);
                wpk[mm][ip][permc(c4 + 1)] = pack2f(wa.y, wb.y);
                wpk[mm][ip][permc(c4 + 2)] = pack2f(wa.z, wb.z);
                wpk[mm][ip][permc(c4 + 3)] = pack2f(wa.w, wb.w);
            }
        }
    }
    for (int e = t; e < 2048; e += 256) {
        int r = e >> 4, ip2 = (e & 15) * 2;
        float4 v = *(const float4*)&feat[(size_t)(rowbase + r) * 64 + ip2 * 2];
        fpk[ip2][r]     = pack2f(v.x, v.y);
        fpk[ip2 + 1][r] = pack2f(v.z, v.w);
    }
    __syncthreads();

    const int rg = t >> 3;
    const int q8 = t & 7;
    const int c0 = q8 * 8;

    float acc[3][4][8];
    {
        const float* Bs[3] = {bq, bk, bv};
#pragma unroll
        for (int m = 0; m < 3; m++)
#pragma unroll
            for (int x = 0; x < 8; x++) {
                float b = Bs[m][x * 8 + q8];
#pragma unroll
                for (int r = 0; r < 4; r++) acc[m][r][x] = b;
            }
    }

#pragma unroll 2
    for (int ip = 0; ip < 32; ip++) {
        uint4 f4 = *(const uint4*)&fpk[ip][rg * 4];
        u32 fr[4] = {f4.x, f4.y, f4.z, f4.w};
#pragma unroll
        for (int m = 0; m < 3; m++) {
            uint4 wv0 = *(const uint4*)&wpk[m][ip][c0];
            uint4 wv1 = *(const uint4*)&wpk[m][ip][c0 + 4];
            u32 wc[8] = {wv0.x, wv0.y, wv0.z, wv0.w, wv1.x, wv1.y, wv1.z, wv1.w};
#pragma unroll
            for (int r = 0; r < 4; r++)
#pragma unroll
                for (int x = 0; x < 8; x++)
                    dot2bf(acc[m][r][x], fr[r], wc[x]);
        }
    }

#pragma unroll
    for (int r = 0; r < 4; r++) {
        int row = rowbase + rg * 4 + r;
        uint4 oq, ok, ov;
        oq.x = cvtpk(acc[0][r][0], acc[0][r][1]); oq.y = cvtpk(acc[0][r][2], acc[0][r][3]);
        oq.z = cvtpk(acc[0][r][4], acc[0][r][5]); oq.w = cvtpk(acc[0][r][6], acc[0][r][7]);
        ok.x = cvtpk(acc[1][r][0], acc[1][r][1]); ok.y = cvtpk(acc[1][r][2], acc[1][r][3]);
        ok.z = cvtpk(acc[1][r][4], acc[1][r][5]); ok.w = cvtpk(acc[1][r][6], acc[1][r][7]);
        ov.x = cvtpk(acc[2][r][0], acc[2][r][1]); ov.y = cvtpk(acc[2][r][2], acc[2][r][3]);
        ov.z = cvtpk(acc[2][r][4], acc[2][r][5]); ov.w = cvtpk(acc[2][r][6], acc[2][r][7]);
        *(uint4*)&qt [(size_t)row * 64 + c0]       = oq;
        *(uint4*)&kvt[(size_t)row * 128 + c0]      = ok;
        *(uint4*)&kvt[(size_t)row * 128 + 64 + c0] = ov;
    }
}

// ===== Kernel 2: fused gather + attention — R16 VERBATIM (best known) =====
// W1 in LDS, P-params in registers, natural allocation (VGPR 80 = 3 waves/SIMD,
// exactly on the reg cliff: <=85 -> 3 waves, >=86 -> 2 waves). Max-sub KEPT
// (load-bearing, R6-R9). No fold (R19: crosses the cliff). No caps (R14/15/17:
// spills). No 2-deep (R13: null). No pk-asm (R12: mov overhead).
__global__ __launch_bounds__(256) void attn_kernel(
    const float* __restrict__ point,
    const int*   __restrict__ idx,
    const u16*   __restrict__ qt,
    const u16*   __restrict__ kvt,
    const float* __restrict__ p_w1,   const float* __restrict__ p_b1,
    const float* __restrict__ p_bn_g, const float* __restrict__ p_bn_b,
    const float* __restrict__ p_bn_m, const float* __restrict__ p_bn_v,
    const float* __restrict__ p_w2,   const float* __restrict__ p_b2,
    const float* __restrict__ w_bn1_g, const float* __restrict__ w_bn1_b,
    const float* __restrict__ w_bn1_m, const float* __restrict__ w_bn1_v,
    const float* __restrict__ w_w1,    const float* __restrict__ w_b1,
    const float* __restrict__ w_bn2_g, const float* __restrict__ w_bn2_b,
    const float* __restrict__ w_bn2_m, const float* __restrict__ w_bn2_v,
    const float* __restrict__ w_w2,    const float* __restrict__ w_b2,
    float* __restrict__ out)
{
    __shared__ u32 lds_w1[8 * 36];   // [l8][36]: 32 used + 4 pad
    const int t  = threadIdx.x;
    const int l8 = t & 7;
    const int n  = blockIdx.x * 32 + (t >> 3);
    const float EPS = 1e-5f;

    // stage w_w1 columns (phi-permuted, bf16-paired): 256 values, 1/thread
    {
        int gl8 = t >> 5, iw = t & 31;
        int p = iw >> 3, r = iw & 7;
        int ce = 16 * p + gl8, co = ce + 8;
        int hh = phi8(r) ^ gl8;
        lds_w1[gl8 * 36 + iw] = pack2f(w_w1[ce * 8 + hh], w_w1[co * 8 + hh]);
    }

    // ---- wave-uniform params (SGPR) ----
    float pw1[9];
#pragma unroll
    for (int i = 0; i < 9; i++) pw1[i] = p_w1[i];
    float pb1b[3], pbs[3], pbh[3];
#pragma unroll
    for (int a = 0; a < 3; a++) {
        float s = p_bn_g[a] * rsqrtf(p_bn_v[a] + EPS);
        pb1b[a] = p_b1[a];
        pbs[a]  = s;
        pbh[a]  = p_bn_b[a] - p_bn_m[a] * s;
    }

    // ---- per-lane register params ----
    f32x2 P0[4], P1[4], P2[4], PB[4];
#pragma unroll
    for (int p = 0; p < 4; p++) {
        int ce = 16 * p + l8, co = ce + 8;
        P0[p] = mk2(p_w2[ce],       p_w2[co]);
        P1[p] = mk2(p_w2[64 + ce],  p_w2[64 + co]);
        P2[p] = mk2(p_w2[128 + ce], p_w2[128 + co]);
        PB[p] = mk2(p_b2[ce],       p_b2[co]);
    }
    // bn2 for this lane's h = l8 only (scalar)
    float b2s_l, b2hh_l;
    {
        float s = w_bn2_g[l8] * rsqrtf(w_bn2_v[l8] + EPS);
        b2s_l  = s;
        b2hh_l = (w_bn2_b[l8] - w_bn2_m[l8] * s) + w_b1[l8] * s;
    }
    // w_w2 column l8, ordered by all-gather slot j: h = phi(j)^l8
    u32 ww2xpk[4];
#pragma unroll
    for (int i = 0; i < 4; i++) {
        int h0 = phi8(2 * i)     ^ l8;
        int h1 = phi8(2 * i + 1) ^ l8;
        ww2xpk[i] = pack2f(w_w2[h0 * 8 + l8], w_w2[h1 * 8 + l8]);
    }
    const float wb2l = w_b2[l8];

    // bn1 scale + offset with q folded: w = relu((k+pj)*s2 + qh2)
    f32x2 s2[4], qh2[4];
    {
        uint4 qr = *(const uint4*)&qt[(size_t)n * 64 + l8 * 8];
        const u32* qw = (const u32*)&qr;
#pragma unroll
        for (int p = 0; p < 4; p++) {
            int ce = 16 * p + l8, co = ce + 8;
            float se = w_bn1_g[ce] * rsqrtf(w_bn1_v[ce] + EPS);
            float so = w_bn1_g[co] * rsqrtf(w_bn1_v[co] + EPS);
            float he = w_bn1_b[ce] - w_bn1_m[ce] * se;
            float ho = w_bn1_b[co] - w_bn1_m[co] * so;
            f32x2 q2 = unpk2(qw[p]);
            s2[p]  = mk2(se, so);
            qh2[p] = mk2(he - q2[0] * se, ho - q2[1] * so);
        }
    }

    const float px = point[n * 3], py = point[n * 3 + 1], pz = point[n * 3 + 2];
    f32x2 acc2[4];
#pragma unroll
    for (int p = 0; p < 4; p++) acc2[p] = mk2(0.f, 0.f);

    __syncthreads();                      // lds_w1 ready
    const u32* wrow = lds_w1 + l8 * 36;   // this lane's w_w1 row base

    // ---- neighbor loop: rolling int4 idx groups, 1-deep kv/point prefetch ----
    uint4 kr, vr;
    float2 jxy;
    float  jz;

    auto proc = [&](int jn) {
        const u16* kpn = kvt + (size_t)jn * 128 + l8 * 8;
        uint4 krn = *(const uint4*)kpn;
        uint4 vrn = *(const uint4*)(kpn + 64);
        float2 jxyn = *(const float2*)&point[jn * 3];
        float  jzn  = point[jn * 3 + 2];

        // linear_p stage 1 (3->3, BN, ReLU)
        float dx = jxy.x - px, dy = jxy.y - py, dz = jz - pz;
        float t0 = fmaxf(0.f, fmaf(fmaf(dz, pw1[6], fmaf(dy, pw1[3], fmaf(dx, pw1[0], pb1b[0]))), pbs[0], pbh[0]));
        float t1 = fmaxf(0.f, fmaf(fmaf(dz, pw1[7], fmaf(dy, pw1[4], fmaf(dx, pw1[1], pb1b[1]))), pbs[1], pbh[1]));
        float t2 = fmaxf(0.f, fmaf(fmaf(dz, pw1[8], fmaf(dy, pw1[5], fmaf(dx, pw1[2], pb1b[2]))), pbs[2], pbh[2]));
        f32x2 tp0 = bc2(t0), tp1 = bc2(t1), tp2 = bc2(t2);

        const u32* kw = (const u32*)&kr;
        float part[8];
#pragma unroll
        for (int h = 0; h < 8; h++) part[h] = 0.f;
        f32x2 pjs[4];

#pragma unroll
        for (int p = 0; p < 4; p++) {
            f32x2 pj = PB[p] + tp0 * P0[p] + tp1 * P1[p] + tp2 * P2[p];
            pjs[p] = pj;
            f32x2 kf = unpk2(kw[p]);
            f32x2 w2 = (kf + pj) * s2[p] + qh2[p];
            u32 wpk_ = cvtpk(fmaxf(w2[0], 0.f), fmaxf(w2[1], 0.f));
            uint4 wa  = *(const uint4*)&wrow[p * 8];
            uint4 wb4 = *(const uint4*)&wrow[p * 8 + 4];
            dot2bf(part[0], wpk_, wa.x);
            dot2bf(part[1], wpk_, wa.y);
            dot2bf(part[2], wpk_, wa.z);
            dot2bf(part[3], wpk_, wa.w);
            dot2bf(part[4], wpk_, wb4.x);
            dot2bf(part[5], wpk_, wb4.y);
            dot2bf(part[6], wpk_, wb4.z);
            dot2bf(part[7], wpk_, wb4.w);
        }
        // reduce-scatter (slots: h = phi(r)^lane; stages xor1, xor2, mirror)
        part[0] += dppf<0xB1>(part[1]);
        part[2] += dppf<0xB1>(part[3]);
        part[4] += dppf<0xB1>(part[5]);
        part[6] += dppf<0xB1>(part[7]);
        part[0] += dppf<0x4E>(part[2]);
        part[4] += dppf<0x4E>(part[6]);
        part[0] += dppf<0x141>(part[4]);
        // scalar bn2 for this lane's h = l8
        float wbl = fmaxf(0.f, fmaf(part[0], b2s_l, b2hh_l));
        // all-gather wb across the 8 lanes (slot j holds wb of h = phi(j)^l8)
        float u1 = dppf<0xB1>(wbl);
        float u2 = dppf<0x4E>(wbl);
        float u3 = dppf<0x4E>(u1);
        float u4 = dppf<0x141>(wbl);
        float u5 = dppf<0x141>(u1);
        float u6 = dppf<0x141>(u2);
        float u7 = dppf<0x141>(u3);
        float y = wb2l;
        dot2bf(y, cvtpk(wbl, u1), ww2xpk[0]);
        dot2bf(y, cvtpk(u2, u3), ww2xpk[1]);
        dot2bf(y, cvtpk(u4, u5), ww2xpk[2]);
        dot2bf(y, cvtpk(u6, u7), ww2xpk[3]);

        // softmax over the 8 lanes — WITH max-subtraction (load-bearing)
        float mx = gmax8(y);
        float e  = __expf(y - mx);
        float ssum = gsum8(e);
        float sm = e * __builtin_amdgcn_rcpf(ssum);
        f32x2 sm2 = bc2(sm);

        const u32* vw = (const u32*)&vr;
#pragma unroll
        for (int p = 0; p < 4; p++) {
            f32x2 vp = unpk2(vw[p]) + pjs[p];
            acc2[p] += sm2 * vp;
        }

        kr = krn; vr = vrn; jxy = jxyn; jz = jzn;
    };

    const int4* idxq = (const int4*)(idx + n * 16);   // 64B-aligned row
    int4 I = idxq[0];
    {
        const u16* kp0 = kvt + (size_t)I.x * 128 + l8 * 8;
        kr  = *(const uint4*)kp0;
        vr  = *(const uint4*)(kp0 + 64);
        jxy = *(const float2*)&point[I.x * 3];
        jz  = point[I.x * 3 + 2];
    }
#pragma unroll
    for (int kg = 0; kg < 4; kg++) {
        int4 In = (kg < 3) ? idxq[kg + 1] : I;   // static offset under unroll
        proc(I.y);
        proc(I.z);
        proc(I.w);
        proc(In.x);   // last group: re-prefetch of a processed nbr, harmless
        I = In;
    }

#pragma unroll
    for (int p = 0; p < 4; p++) {
        out[(size_t)n * 64 + 16 * p + l8]     = acc2[p][0];
        out[(size_t)n * 64 + 16 * p + 8 + l8] = acc2[p][1];
    }
}

extern "C" void kernel_launch(void* const* d_in, const int* in_sizes, int n_in,
                              void* d_out, int out_size, void* d_ws, size_t ws_size,
                              hipStream_t stream)
{
    const float* point   = (const float*)d_in[0];
    const float* feat    = (const float*)d_in[1];
    const int*   idx     = (const int*)d_in[2];
    const float* Wq      = (const float*)d_in[3];
    const float* bq      = (const float*)d_in[4];
    const float* Wk      = (const float*)d_in[5];
    const float* bk      = (const float*)d_in[6];
    const float* Wv      = (const float*)d_in[7];
    const float* bv      = (const float*)d_in[8];
    const float* p_w1    = (const float*)d_in[9];
    const float* p_b1    = (const float*)d_in[10];
    const float* p_bn_g  = (const float*)d_in[11];
    const float* p_bn_b  = (const float*)d_in[12];
    const float* p_bn_m  = (const float*)d_in[13];
    const float* p_bn_v  = (const float*)d_in[14];
    const float* p_w2    = (const float*)d_in[15];
    const float* p_b2    = (const float*)d_in[16];
    const float* w_bn1_g = (const float*)d_in[17];
    const float* w_bn1_b = (const float*)d_in[18];
    const float* w_bn1_m = (const float*)d_in[19];
    const float* w_bn1_v = (const float*)d_in[20];
    const float* w_w1    = (const float*)d_in[21];
    const float* w_b1    = (const float*)d_in[22];
    const float* w_bn2_g = (const float*)d_in[23];
    const float* w_bn2_b = (const float*)d_in[24];
    const float* w_bn2_m = (const float*)d_in[25];
    const float* w_bn2_v = (const float*)d_in[26];
    const float* w_w2    = (const float*)d_in[27];
    const float* w_b2    = (const float*)d_in[28];
    float* out = (float*)d_out;

    const int N = in_sizes[0] / 3;   // 65536

    u16* kvt = (u16*)d_ws;                       // N*128 bf16
    u16* qt  = (u16*)d_ws + (size_t)N * 128;     // N*64 bf16

    qkv_kernel<<<N / 128, 256, 0, stream>>>(feat, Wq, bq, Wk, bk, Wv, bv, qt, kvt);
    attn_kernel<<<N / 32, 256, 0, stream>>>(point, idx, qt, kvt,
                                            p_w1, p_b1, p_bn_g, p_bn_b, p_bn_m, p_bn_v, p_w2, p_b2,
                                            w_bn1_g, w_bn1_b, w_bn1_m, w_bn1_v, w_w1, w_b1,
                                            w_bn2_g, w_bn2_b, w_bn2_m, w_bn2_v, w_w2, w_b2,
                                            out);
}